// Round 11
// baseline (1919.523 us; speedup 1.0000x reference)
//
#include <hip/hip_runtime.h>
#include <hip/hip_bf16.h>
#include <math.h>

#define BB 64
#define HW 196
#define FEAT 2048
#define EMB 512
#define HID 1024
#define ATT 512
#define VOCAB 10000
#define TT 20
#define STEPS 19

using bfrag = __attribute__((ext_vector_type(8))) short;   // 8 bf16 = 4 VGPR
using f32x4 = __attribute__((ext_vector_type(4))) float;

__device__ __forceinline__ float sigmoid_fast(float x) { return 1.0f / (1.0f + __expf(-x)); }
__device__ __forceinline__ float tanh_fast(float x) {
    float e = __expf(2.0f * x);
    return 1.0f - 2.0f / (e + 1.0f);
}
__device__ __forceinline__ ushort f2bf_rne(float f) {
    unsigned u = __float_as_uint(f);
    unsigned r = (u + 0x7FFFu + ((u >> 16) & 1u)) >> 16;
    return (ushort)r;
}
__device__ __forceinline__ float bf2f(ushort h) {
    return __uint_as_float(((unsigned)h) << 16);
}
// XOR bank swizzle for 16B LDS chunks (R10-verified conflict-free):
// chunk = row*4 + (g ^ ((row>>1)&3)); slot within any 8-lane window is a
// permutation of 0..7 on both staging writes and fragment reads.
__device__ __forceinline__ int sw_idx(int row, int g) { return row * 4 + (g ^ ((row >> 1) & 3)); }

// ---------------------------------------------------------------------------
// fp32 -> split bf16 planes: x = hi + lo.  n % 1024 == 0.
// ---------------------------------------------------------------------------
__global__ __launch_bounds__(256) void k_split(const float* __restrict__ x,
                                               ushort* __restrict__ hi,
                                               ushort* __restrict__ lo, int n)
{
    int i4 = (blockIdx.x * 256 + threadIdx.x) * 4;
    if (i4 >= n) return;
    float4 v = *(const float4*)(x + i4);
    float av[4] = {v.x, v.y, v.z, v.w};
    #pragma unroll
    for (int j = 0; j < 4; ++j) {
        ushort h = f2bf_rne(av[j]);
        hi[i4 + j] = h;
        lo[i4 + j] = f2bf_rne(av[j] - bf2f(h));
    }
}

// ---------------------------------------------------------------------------
// mfma_g: split-bf16 NT GEMM, 64(M) x 128(N) tile, BK=32, 4 waves.
// 3-term: Ah*Bh + Ah*Bl + Al*Bh. A always fp32 (split during staging).
// BF32B: B fp32, converted during staging; else B = pre-split planes (Bld
// leading dim, may exceed K for column slices). Register-prefetch double
// buffer: next chunk's global loads issue right after the store barrier and
// complete under the MFMA of the current chunk (T14).
// LDS XOR-swizzled (sw_idx, conflict-free). T1 bijective XCD swizzle.
// NFAST: consecutive swizzled blocks share the m-panel; else n-panel.
// M multiple of 64; N ragged OK.
// ---------------------------------------------------------------------------
template<bool BF32B, bool NFAST>
__global__ __launch_bounds__(256) void mfma_g(
    const float* __restrict__ A,
    const float* __restrict__ Bf,
    const ushort* __restrict__ Bhi, const ushort* __restrict__ Blo,
    const float* __restrict__ bias, float* __restrict__ C,
    int N, int K, int Bld, int ldc, int NXB, int NMB)
{
    __shared__ __align__(16) ushort sAh[256 * 8];
    __shared__ __align__(16) ushort sAl[256 * 8];
    __shared__ __align__(16) ushort sBh[512 * 8];
    __shared__ __align__(16) ushort sBl[512 * 8];

    const int tid = threadIdx.x;

    // XCD-chunked bijective swizzle
    const int nwg = NXB * NMB;
    const int q = nwg >> 3, r = nwg & 7;
    const int xcd = blockIdx.x & 7, sidx = blockIdx.x >> 3;
    const int wg = (xcd < r) ? (xcd * (q + 1) + sidx)
                             : (r * (q + 1) + (xcd - r) * q + sidx);
    int im, inb;
    if (NFAST) { inb = wg % NXB; im = wg / NXB; }
    else       { im = wg % NMB; inb = wg / NMB; }
    const int m0 = im * 64;
    const int n0 = inb * 128;

    const int lane = tid & 63;
    const int w = tid >> 6;
    const int mh = (w & 1) * 32;
    const int nh = (w >> 1) * 64;
    const int g = lane >> 4, l15 = lane & 15;

    // staging descriptors
    const int rA = tid >> 2, gA = tid & 3;
    const float* apA = A + (size_t)(m0 + rA) * K + gA * 8;
    const int cA = sw_idx(rA, gA) * 8;

    const float* apBf[2]; int cBf[2];
    const ushort* apBp[4]; int cBp[4];
    if (BF32B) {
        #pragma unroll
        for (int i = 0; i < 2; ++i) {
            int c = tid + i * 256;
            int r_ = c >> 2, g_ = c & 3;
            int brow = min(n0 + r_, N - 1);
            apBf[i] = Bf + (size_t)brow * Bld + g_ * 8;
            cBf[i] = sw_idx(r_, g_) * 8;
        }
    } else {
        #pragma unroll
        for (int i = 0; i < 4; ++i) {
            int c = tid + i * 256;
            int pl = i >> 1;               // i=0,1 -> hi; i=2,3 -> lo
            int idx2 = c & 511;
            int r_ = idx2 >> 2, g_ = idx2 & 3;
            int brow = min(n0 + r_, N - 1);
            apBp[i] = (pl ? Blo : Bhi) + (size_t)brow * Bld + g_ * 8;
            cBp[i] = sw_idx(r_, g_) * 8;
        }
    }

    float a_reg[8];
    float bf_reg[16];
    bfrag bp_reg[4];

    auto load_chunk = [&](int kk) {
        *(float4*)(a_reg)     = *(const float4*)(apA + kk);
        *(float4*)(a_reg + 4) = *(const float4*)(apA + kk + 4);
        if constexpr (BF32B) {
            #pragma unroll
            for (int i = 0; i < 2; ++i) {
                *(float4*)(bf_reg + i * 8)     = *(const float4*)(apBf[i] + kk);
                *(float4*)(bf_reg + i * 8 + 4) = *(const float4*)(apBf[i] + kk + 4);
            }
        } else {
            #pragma unroll
            for (int i = 0; i < 4; ++i)
                bp_reg[i] = *(const bfrag*)(apBp[i] + kk);
        }
    };

    f32x4 acc[2][4] = {};
    load_chunk(0);

    for (int k0 = 0; k0 < K; k0 += 32) {
        __syncthreads();   // previous chunk's fragment reads complete
        {   // A: convert + swizzled store
            bfrag vh, vl;
            #pragma unroll
            for (int j = 0; j < 8; ++j) {
                ushort h = f2bf_rne(a_reg[j]);
                vh[j] = (short)h;
                vl[j] = (short)f2bf_rne(a_reg[j] - bf2f(h));
            }
            *(bfrag*)&sAh[cA] = vh;
            *(bfrag*)&sAl[cA] = vl;
        }
        if constexpr (BF32B) {
            #pragma unroll
            for (int i = 0; i < 2; ++i) {
                bfrag vh, vl;
                #pragma unroll
                for (int j = 0; j < 8; ++j) {
                    float v = bf_reg[i * 8 + j];
                    ushort h = f2bf_rne(v);
                    vh[j] = (short)h;
                    vl[j] = (short)f2bf_rne(v - bf2f(h));
                }
                *(bfrag*)&sBh[cBf[i]] = vh;
                *(bfrag*)&sBl[cBf[i]] = vl;
            }
        } else {
            *(bfrag*)&sBh[cBp[0]] = bp_reg[0];
            *(bfrag*)&sBh[cBp[1]] = bp_reg[1];
            *(bfrag*)&sBl[cBp[2]] = bp_reg[2];
            *(bfrag*)&sBl[cBp[3]] = bp_reg[3];
        }
        __syncthreads();

        if (k0 + 32 < K) load_chunk(k0 + 32);   // overlaps MFMA below

        bfrag ah[2], al[2], bh[4], bl[4];
        #pragma unroll
        for (int s = 0; s < 2; ++s) {
            int c = sw_idx(mh + s * 16 + l15, g) * 8;
            ah[s] = *(const bfrag*)&sAh[c];
            al[s] = *(const bfrag*)&sAl[c];
        }
        #pragma unroll
        for (int u = 0; u < 4; ++u) {
            int c = sw_idx(nh + u * 16 + l15, g) * 8;
            bh[u] = *(const bfrag*)&sBh[c];
            bl[u] = *(const bfrag*)&sBl[c];
        }
        #pragma unroll
        for (int s = 0; s < 2; ++s)
            #pragma unroll
            for (int u = 0; u < 4; ++u) {
                acc[s][u] = __builtin_amdgcn_mfma_f32_16x16x32_bf16(ah[s], bh[u], acc[s][u], 0, 0, 0);
                acc[s][u] = __builtin_amdgcn_mfma_f32_16x16x32_bf16(ah[s], bl[u], acc[s][u], 0, 0, 0);
                acc[s][u] = __builtin_amdgcn_mfma_f32_16x16x32_bf16(al[s], bh[u], acc[s][u], 0, 0, 0);
            }
    }

    #pragma unroll
    for (int s = 0; s < 2; ++s)
        #pragma unroll
        for (int u = 0; u < 4; ++u) {
            int col = n0 + nh + u * 16 + l15;
            if (col < N) {
                float bv = bias ? bias[col] : 0.f;
                #pragma unroll
                for (int rr = 0; rr < 4; ++rr) {
                    int row = m0 + mh + s * 16 + g * 4 + rr;
                    C[(size_t)row * ldc + col] = acc[s][u][rr] + bv;
                }
            }
        }
}

// ---------------------------------------------------------------------------
// k_fmean2: fmean[b][e] = mean_h f[b][h][e].  grid 256 (b*4+eq, 128 e each).
// ---------------------------------------------------------------------------
__global__ __launch_bounds__(256) void k_fmean2(const float* __restrict__ f,
                                                float* __restrict__ fmean)
{
    __shared__ float part[128];
    int blk = blockIdx.x;
    int b = blk >> 2, eq = blk & 3;
    int el = threadIdx.x & 127, half = threadIdx.x >> 7;
    int e = eq * 128 + el;
    const float* fb = f + (size_t)b * HW * EMB + e;
    float s = 0.f;
    int h0 = half * 98;
    for (int h = h0; h < h0 + 98; ++h) s += fb[(size_t)h * EMB];
    if (half) part[el] = s;
    __syncthreads();
    if (!half) fmean[b * EMB + e] = (s + part[el]) * (1.0f / HW);
}

// ---------------------------------------------------------------------------
// k_init2: hx0/cx0 = fmean @ {W_hi,W_ci}^T + bias.  grid 512 x 256 thr,
// 1 thread per output (K=512 dot). Also writes the initial hx bf16 planes.
// ---------------------------------------------------------------------------
__global__ __launch_bounds__(256) void k_init2(
    const float* __restrict__ fmean,
    const float* __restrict__ W_hi, const float* __restrict__ b_hi,
    const float* __restrict__ W_ci, const float* __restrict__ b_ci,
    float* __restrict__ hx, float* __restrict__ cx,
    ushort* __restrict__ hxp_h, ushort* __restrict__ hxp_l)
{
    int o = blockIdx.x * 256 + threadIdx.x;   // 0..131071
    int b = o >> 11, uu = o & 2047;
    bool isC = uu >= 1024;
    int u = uu & 1023;
    const float4* wr = (const float4*)((isC ? W_ci : W_hi) + (size_t)u * EMB);
    const float4* fm = (const float4*)(fmean + (size_t)b * EMB);
    float s = isC ? b_ci[u] : b_hi[u];
    #pragma unroll 8
    for (int k = 0; k < EMB / 4; ++k) {
        float4 wv = wr[k], xv = fm[k];
        s += wv.x*xv.x + wv.y*xv.y + wv.z*xv.z + wv.w*xv.w;
    }
    int idx = b * HID + u;
    if (isC) cx[idx] = s;
    else {
        hx[idx] = s;
        ushort hh = f2bf_rne(s);
        hxp_h[idx] = hh;
        hxp_l[idx] = f2bf_rne(s - bf2f(hh));
    }
}

// xs_f[t*64+b][:] = E[captions[b][t]][:]  (fp32; feeds the hoisted GEMM)
__global__ __launch_bounds__(128) void k_embed(const int* __restrict__ cap,
                                               const float* __restrict__ E,
                                               float* __restrict__ xs_f)
{
    int blk = blockIdx.x;
    int t = blk / BB, b = blk % BB;
    int c = cap[b * TT + t];
    const float4* src = (const float4*)(E + (size_t)c * EMB);
    float4* dst = (float4*)(xs_f + ((size_t)t * BB + b) * EMB);
    dst[threadIdx.x] = src[threadIdx.x];
}

// ---------------------------------------------------------------------------
// k_ha: ha[b][a] = hx[b].W2[a] + b2[a].  grid 256: block -> 16 a's x 8 b's.
// ---------------------------------------------------------------------------
__global__ __launch_bounds__(256) void k_ha(
    const float* __restrict__ hx, const float* __restrict__ W2,
    const float* __restrict__ b2, float* __restrict__ ha)
{
    __shared__ __align__(16) float hx_s[8][1028];
    __shared__ float part[256];
    const int tid = threadIdx.x;
    const int a0 = (blockIdx.x >> 3) * 16;
    const int b0 = (blockIdx.x & 7) * 8;

    for (int i = tid; i < 8 * 256; i += 256) {
        int r = i >> 8, c4 = i & 255;
        *(float4*)&hx_s[r][c4 * 4] = *(const float4*)(hx + (size_t)(b0 + r) * HID + c4 * 4);
    }
    __syncthreads();

    const int a_i = tid >> 4;
    const int b_i = (tid >> 1) & 7;
    const int half = tid & 1;
    const float4* wr = (const float4*)(W2 + (size_t)(a0 + a_i) * HID + half * 512);
    const float* xr = &hx_s[b_i][half * 512];
    float s = 0.f;
    #pragma unroll 8
    for (int i = 0; i < 128; ++i) {
        float4 w = wr[i];
        float4 x = *(const float4*)(xr + i * 4);
        s += w.x*x.x + w.y*x.y + w.z*x.z + w.w*x.w;
    }
    part[tid] = s;
    __syncthreads();
    if (!half)
        ha[(size_t)(b0 + b_i) * ATT + a0 + a_i] = part[tid] + part[tid + 1] + b2[a0 + a_i];
}

// ---------------------------------------------------------------------------
// k_logits: grid 256 (b*4+q, 49 h each). bV omitted (softmax-invariant).
// ---------------------------------------------------------------------------
__global__ __launch_bounds__(256) void k_logits(
    const float* __restrict__ fa, const float* __restrict__ ha,
    const float* __restrict__ V, float* __restrict__ logits)
{
    int blk = blockIdx.x;
    int b = blk >> 2, q = blk & 3;
    int tid = threadIdx.x;
    __shared__ float ha_s[ATT];
    __shared__ float V_s[ATT];
    for (int i = tid; i < ATT; i += 256) { ha_s[i] = ha[b * ATT + i]; V_s[i] = V[i]; }
    __syncthreads();

    int wid = tid >> 6, lane = tid & 63;
    for (int h = q * 49 + wid; h < q * 49 + 49; h += 4) {
        const float4* fr = (const float4*)(fa + ((size_t)b * HW + h) * ATT);
        float s = 0.f;
        #pragma unroll
        for (int i = 0; i < 2; ++i) {
            int i4 = lane + (i << 6);
            float4 fv = fr[i4];
            float4 hv = *(const float4*)&ha_s[i4 * 4];
            float4 vv = *(const float4*)&V_s[i4 * 4];
            s += tanh_fast(fv.x + hv.x) * vv.x + tanh_fast(fv.y + hv.y) * vv.y
               + tanh_fast(fv.z + hv.z) * vv.z + tanh_fast(fv.w + hv.w) * vv.w;
        }
        #pragma unroll
        for (int off = 32; off > 0; off >>= 1) s += __shfl_down(s, off);
        if (lane == 0) logits[b * HW + h] = s;
    }
}

// ---------------------------------------------------------------------------
// k_ctx: grid 256 (b*4+eg, 128 e each). Softmax recomputed per block;
// ctx -> split bf16 planes.
// ---------------------------------------------------------------------------
__global__ __launch_bounds__(256) void k_ctx(
    const float* __restrict__ logits, const float* __restrict__ f,
    ushort* __restrict__ ctx_hi, ushort* __restrict__ ctx_lo)
{
    int blk = blockIdx.x;
    int b = blk >> 2, eg = blk & 3;
    int tid = threadIdx.x;
    __shared__ float w_s[HW];
    __shared__ float red_s[256];
    __shared__ float part[128];

    float v = (tid < HW) ? logits[b * HW + tid] : -INFINITY;
    red_s[tid] = v; __syncthreads();
    for (int s = 128; s > 0; s >>= 1) {
        if (tid < s) red_s[tid] = fmaxf(red_s[tid], red_s[tid + s]);
        __syncthreads();
    }
    float mx = red_s[0]; __syncthreads();
    float e = (tid < HW) ? __expf(v - mx) : 0.f;
    red_s[tid] = e; __syncthreads();
    for (int s = 128; s > 0; s >>= 1) {
        if (tid < s) red_s[tid] += red_s[tid + s];
        __syncthreads();
    }
    float inv = 1.0f / red_s[0];
    if (tid < HW) w_s[tid] = e * inv;
    __syncthreads();

    int e0 = (eg << 7) + (tid & 127);
    int half = tid >> 7;
    const float* fb = f + (size_t)b * HW * EMB + e0;
    float s = 0.f;
    int h0 = half * 98;
    for (int h = h0; h < h0 + 98; ++h)
        s = fmaf(w_s[h], fb[(size_t)h * EMB], s);
    if (half) part[tid & 127] = s;
    __syncthreads();
    if (!half) {
        float c = s + part[tid];
        ushort ch = f2bf_rne(c);
        ctx_hi[b * EMB + e0] = ch;
        ctx_lo[b * EMB + e0] = f2bf_rne(c - bf2f(ch));
    }
}

// ---------------------------------------------------------------------------
// k_gates_lstm: recurrent half of the gates GEMM (K=1536: ctx 512 + hx 1024;
// the xs.W_ih[:, :512] term is precomputed in gxs) + fused LSTM.
// grid 256 x 512 thr (8 waves). Wave (mt, kh): kh0 = ctx + hx[0:256) (24 kk),
// kh1 = hx[256:1024) (24 kk) -- balanced. ncol(l15) = (l15>>2)*1024 + bk*4 +
// (l15&3). Epilogue: 8KB LDS reduce + gxs + biases -> LSTM -> hx, cx,
// next hx planes (parity double-buffered), hx_all fp32.
// ---------------------------------------------------------------------------
__global__ __launch_bounds__(512) void k_gates_lstm(
    const float* __restrict__ gxs_t,                                  // [64][4096]
    const ushort* __restrict__ cth, const ushort* __restrict__ ctl,   // [64][512]
    const ushort* __restrict__ hxh, const ushort* __restrict__ hxl,   // [64][1024] read
    const ushort* __restrict__ wihh, const ushort* __restrict__ wihl, // [4096][1024]
    const ushort* __restrict__ whhh, const ushort* __restrict__ whhl, // [4096][1024]
    const float* __restrict__ b_ih, const float* __restrict__ b_hh,
    float* __restrict__ hx, float* __restrict__ cx,
    ushort* __restrict__ nxh, ushort* __restrict__ nxl,               // write planes
    float* __restrict__ hx_all_t)
{
    __shared__ float sg[2][64][16];   // 8 KB
    const int tid = threadIdx.x, bk = blockIdx.x;
    const int lane = tid & 63, wid = tid >> 6;
    const int mt = wid & 3, kh = wid >> 2;
    const int l15 = lane & 15, g = lane >> 4;
    const int arow = mt * 16 + l15;
    const int ncol = (l15 >> 2) * 1024 + bk * 4 + (l15 & 3);
    const int koff = g * 8;

    f32x4 acc0 = {}, acc1 = {};

    if (kh == 0) {
        {   // ctx . W_ih[:, 512:1024)  (16 kk)
            const ushort* ah = cth + (size_t)arow * 512 + koff;
            const ushort* al = ctl + (size_t)arow * 512 + koff;
            const ushort* bh = wihh + (size_t)ncol * 1024 + 512 + koff;
            const ushort* bl = wihl + (size_t)ncol * 1024 + 512 + koff;
            #pragma unroll 4
            for (int kk = 0; kk < 16; ++kk) {
                bfrag a_h = *(const bfrag*)(ah + kk * 32);
                bfrag a_l = *(const bfrag*)(al + kk * 32);
                bfrag b_h = *(const bfrag*)(bh + kk * 32);
                bfrag b_l = *(const bfrag*)(bl + kk * 32);
                acc0 = __builtin_amdgcn_mfma_f32_16x16x32_bf16(a_h, b_h, acc0, 0, 0, 0);
                acc1 = __builtin_amdgcn_mfma_f32_16x16x32_bf16(a_h, b_l, acc1, 0, 0, 0);
                acc1 = __builtin_amdgcn_mfma_f32_16x16x32_bf16(a_l, b_h, acc1, 0, 0, 0);
            }
        }
        {   // hx[0:256) . W_hh[:, 0:256)  (8 kk)
            const ushort* ah = hxh + (size_t)arow * 1024 + koff;
            const ushort* al = hxl + (size_t)arow * 1024 + koff;
            const ushort* bh = whhh + (size_t)ncol * 1024 + koff;
            const ushort* bl = whhl + (size_t)ncol * 1024 + koff;
            #pragma unroll 4
            for (int kk = 0; kk < 8; ++kk) {
                bfrag a_h = *(const bfrag*)(ah + kk * 32);
                bfrag a_l = *(const bfrag*)(al + kk * 32);
                bfrag b_h = *(const bfrag*)(bh + kk * 32);
                bfrag b_l = *(const bfrag*)(bl + kk * 32);
                acc0 = __builtin_amdgcn_mfma_f32_16x16x32_bf16(a_h, b_h, acc0, 0, 0, 0);
                acc1 = __builtin_amdgcn_mfma_f32_16x16x32_bf16(a_h, b_l, acc1, 0, 0, 0);
                acc1 = __builtin_amdgcn_mfma_f32_16x16x32_bf16(a_l, b_h, acc1, 0, 0, 0);
            }
        }
    } else {
        // hx[256:1024) . W_hh[:, 256:1024)  (24 kk)
        const ushort* ah = hxh + (size_t)arow * 1024 + 256 + koff;
        const ushort* al = hxl + (size_t)arow * 1024 + 256 + koff;
        const ushort* bh = whhh + (size_t)ncol * 1024 + 256 + koff;
        const ushort* bl = whhl + (size_t)ncol * 1024 + 256 + koff;
        #pragma unroll 4
        for (int kk = 0; kk < 24; ++kk) {
            bfrag a_h = *(const bfrag*)(ah + kk * 32);
            bfrag a_l = *(const bfrag*)(al + kk * 32);
            bfrag b_h = *(const bfrag*)(bh + kk * 32);
            bfrag b_l = *(const bfrag*)(bl + kk * 32);
            acc0 = __builtin_amdgcn_mfma_f32_16x16x32_bf16(a_h, b_h, acc0, 0, 0, 0);
            acc1 = __builtin_amdgcn_mfma_f32_16x16x32_bf16(a_h, b_l, acc1, 0, 0, 0);
            acc1 = __builtin_amdgcn_mfma_f32_16x16x32_bf16(a_l, b_h, acc1, 0, 0, 0);
        }
    }

    #pragma unroll
    for (int rr = 0; rr < 4; ++rr)
        sg[kh][mt * 16 + g * 4 + rr][l15] = acc0[rr] + acc1[rr];
    __syncthreads();

    if (tid < 256) {
        int b = tid >> 2, uu = tid & 3;
        int u = bk * 4 + uu;
        const float* gx = gxs_t + (size_t)b * 4096;
        float gi = sg[0][b][uu]      + sg[1][b][uu]      + gx[u]        + b_ih[u]        + b_hh[u];
        float gf = sg[0][b][4 + uu]  + sg[1][b][4 + uu]  + gx[1024 + u] + b_ih[1024 + u] + b_hh[1024 + u];
        float gg = sg[0][b][8 + uu]  + sg[1][b][8 + uu]  + gx[2048 + u] + b_ih[2048 + u] + b_hh[2048 + u];
        float go = sg[0][b][12 + uu] + sg[1][b][12 + uu] + gx[3072 + u] + b_ih[3072 + u] + b_hh[3072 + u];
        int idx = b * 1024 + u;
        float c = sigmoid_fast(gf) * cx[idx] + sigmoid_fast(gi) * tanh_fast(gg);
        float h = sigmoid_fast(go) * tanh_fast(c);
        cx[idx] = c;
        hx[idx] = h;
        hx_all_t[idx] = h;
        ushort hh = f2bf_rne(h);
        nxh[idx] = hh;
        nxl[idx] = f2bf_rne(h - bf2f(hh));
    }
}

// ---------------------------------------------------------------------------
extern "C" void kernel_launch(void* const* d_in, const int* in_sizes, int n_in,
                              void* d_out, int out_size, void* d_ws, size_t ws_size,
                              hipStream_t stream) {
    const float* features = (const float*)d_in[0];
    const int*   captions = (const int*)d_in[1];
    const float* E      = (const float*)d_in[3];
    const float* W_feat = (const float*)d_in[4];
    const float* b_feat = (const float*)d_in[5];
    const float* W1     = (const float*)d_in[6];
    const float* b1     = (const float*)d_in[7];
    const float* W2     = (const float*)d_in[8];
    const float* b2     = (const float*)d_in[9];
    const float* V      = (const float*)d_in[10];
    // d_in[11] bV: softmax-invariant, unused
    const float* W_hi   = (const float*)d_in[12];
    const float* b_hi   = (const float*)d_in[13];
    const float* W_ci   = (const float*)d_in[14];
    const float* b_ci   = (const float*)d_in[15];
    const float* W_ih   = (const float*)d_in[16];
    const float* b_ih   = (const float*)d_in[17];
    const float* W_hh   = (const float*)d_in[18];
    const float* b_hh   = (const float*)d_in[19];
    const float* W_out  = (const float*)d_in[20];
    const float* b_out  = (const float*)d_in[21];
    float* out = (float*)d_out;

    // ---- workspace layout ----
    float* ws = (float*)d_ws;
    float* f_buf   = ws;                          // 6,422,528
    float* fa_buf  = f_buf + 6422528;             // 6,422,528
    float* fmean   = fa_buf + 6422528;            // 32,768
    float* hx      = fmean + 32768;               // 65,536
    float* cx      = hx + 65536;                  // 65,536
    float* hx_all  = cx + 65536;                  // 1,310,720
    float* ha      = hx_all + 1310720;            // 32,768
    float* logits  = ha + 32768;                  // 12,544 (+pad)
    float* xs_f    = logits + 16384;              // 622,592
    float* gxs     = xs_f + 622592;               // 1216*4096 = 4,980,736
    ushort* p = (ushort*)(gxs + 4980736);
    ushort* wih_hi   = p;            p += 4194304;
    ushort* wih_lo   = p;            p += 4194304;
    ushort* whh_hi   = p;            p += 4194304;
    ushort* whh_lo   = p;            p += 4194304;
    ushort* ctx_hi   = p;            p += 32768;
    ushort* ctx_lo   = p;            p += 32768;
    ushort* hxp      = p;            p += 262144;   // [2 bufs][hi|lo][65536]

    // ---- precompute ----
    k_split<<<4194304 / 4 / 256, 256, 0, stream>>>(W_ih, wih_hi, wih_lo, 4194304);
    k_split<<<4194304 / 4 / 256, 256, 0, stream>>>(W_hh, whh_hi, whh_lo, 4194304);
    k_embed<<<STEPS * BB, 128, 0, stream>>>(captions, E, xs_f);
    // f = features @ W_feat^T + b_feat  [12544,512], K=2048 (fp32 B)
    mfma_g<true, true><<<784, 256, 0, stream>>>(
        features, W_feat, nullptr, nullptr, b_feat, f_buf, 512, 2048, 2048, 512, 4, 196);
    // fa = f @ W1^T + b1  [12544,512], K=512 (fp32 B)
    mfma_g<true, true><<<784, 256, 0, stream>>>(
        f_buf, W1, nullptr, nullptr, b1, fa_buf, 512, 512, 512, 512, 4, 196);
    // gxs = xs_flat @ W_ih[:, 0:512]^T  [1216,4096], K=512, Bld=1024 (planes)
    mfma_g<false, false><<<608, 256, 0, stream>>>(
        xs_f, nullptr, wih_hi, wih_lo, nullptr, gxs, 4096, 512, 1024, 4096, 32, 19);
    k_fmean2<<<256, 256, 0, stream>>>(f_buf, fmean);
    k_init2<<<512, 256, 0, stream>>>(fmean, W_hi, b_hi, W_ci, b_ci,
                                     hx, cx, hxp, hxp + 65536);

    // ---- recurrent steps: 4 full-chip dispatches per step ----
    for (int t = 0; t < STEPS; ++t) {
        ushort* hx_rd = hxp + (size_t)(t & 1) * 131072;
        ushort* hx_wr = hxp + (size_t)((t + 1) & 1) * 131072;
        k_ha<<<256, 256, 0, stream>>>(hx, W2, b2, ha);
        k_logits<<<256, 256, 0, stream>>>(fa_buf, ha, V, logits);
        k_ctx<<<256, 256, 0, stream>>>(logits, f_buf, ctx_hi, ctx_lo);
        k_gates_lstm<<<256, 512, 0, stream>>>(
            gxs + (size_t)t * BB * 4096,
            ctx_hi, ctx_lo, hx_rd, hx_rd + 65536,
            wih_hi, wih_lo, whh_hi, whh_lo, b_ih, b_hh,
            hx, cx, hx_wr, hx_wr + 65536,
            hx_all + (size_t)t * BB * HID);
    }

    // ---- vocab projection over all steps: [1216,10000], K=1024 (fp32 B) ----
    mfma_g<true, false><<<1501, 256, 0, stream>>>(
        hx_all, W_out, nullptr, nullptr, b_out, out, VOCAB, HID, 1024, VOCAB, 79, 19);
}

// Round 12
// 1572.797 us; speedup vs baseline: 1.2205x; 1.2205x over previous
//
#include <hip/hip_runtime.h>
#include <hip/hip_bf16.h>
#include <math.h>

#define BB 64
#define HW 196
#define FEAT 2048
#define EMB 512
#define HID 1024
#define ATT 512
#define VOCAB 10000
#define TT 20
#define STEPS 19

using bfrag = __attribute__((ext_vector_type(8))) short;   // 8 bf16 = 4 VGPR
using f32x4 = __attribute__((ext_vector_type(4))) float;

__device__ __forceinline__ float sigmoid_fast(float x) { return 1.0f / (1.0f + __expf(-x)); }
__device__ __forceinline__ float tanh_fast(float x) {
    float e = __expf(2.0f * x);
    return 1.0f - 2.0f / (e + 1.0f);
}
__device__ __forceinline__ ushort f2bf_rne(float f) {
    unsigned u = __float_as_uint(f);
    unsigned r = (u + 0x7FFFu + ((u >> 16) & 1u)) >> 16;
    return (ushort)r;
}
__device__ __forceinline__ float bf2f(ushort h) {
    return __uint_as_float(((unsigned)h) << 16);
}
// XOR bank swizzle for 16B LDS chunks (R10-verified conflict-free):
// chunk = row*4 + (g ^ ((row>>1)&3)); slot within any 8-lane window is a
// permutation of 0..7 on both staging writes and fragment reads.
__device__ __forceinline__ int sw_idx(int row, int g) { return row * 4 + (g ^ ((row >> 1) & 3)); }

// ---------------------------------------------------------------------------
// fp32 -> split bf16 planes: x = hi + lo.  n % 1024 == 0.
// ---------------------------------------------------------------------------
__global__ __launch_bounds__(256) void k_split(const float* __restrict__ x,
                                               ushort* __restrict__ hi,
                                               ushort* __restrict__ lo, int n)
{
    int i4 = (blockIdx.x * 256 + threadIdx.x) * 4;
    if (i4 >= n) return;
    float4 v = *(const float4*)(x + i4);
    float av[4] = {v.x, v.y, v.z, v.w};
    #pragma unroll
    for (int j = 0; j < 4; ++j) {
        ushort h = f2bf_rne(av[j]);
        hi[i4 + j] = h;
        lo[i4 + j] = f2bf_rne(av[j] - bf2f(h));
    }
}

// ---------------------------------------------------------------------------
// mfma_g (R10-verified: 148us f, 0 conflicts, VGPR 52): split-bf16 NT GEMM,
// 64(M) x 128(N) tile, BK=32, 4 waves. 3-term: Ah*Bh + Ah*Bl + Al*Bh.
// A fp32 (split during staging); B pre-split planes, leading dim Bld.
// LDS XOR-swizzled (sw_idx). T1 bijective XCD swizzle.
// NFAST: consecutive swizzled blocks share the m-panel; else n-panel.
// ---------------------------------------------------------------------------
template<bool NFAST>
__global__ __launch_bounds__(256) void mfma_g(
    const float* __restrict__ A,
    const ushort* __restrict__ Bhi, const ushort* __restrict__ Blo,
    const float* __restrict__ bias, float* __restrict__ C,
    int N, int K, int Bld, int ldc, int NXB, int NMB)
{
    __shared__ __align__(16) ushort sAh[256 * 8];
    __shared__ __align__(16) ushort sAl[256 * 8];
    __shared__ __align__(16) ushort sBh[512 * 8];
    __shared__ __align__(16) ushort sBl[512 * 8];

    const int tid = threadIdx.x;

    const int nwg = NXB * NMB;
    const int q = nwg >> 3, r = nwg & 7;
    const int xcd = blockIdx.x & 7, sidx = blockIdx.x >> 3;
    const int wg = (xcd < r) ? (xcd * (q + 1) + sidx)
                             : (r * (q + 1) + (xcd - r) * q + sidx);
    int im, inb;
    if (NFAST) { inb = wg % NXB; im = wg / NXB; }
    else       { im = wg % NMB; inb = wg / NMB; }
    const int m0 = im * 64;
    const int n0 = inb * 128;

    const int lane = tid & 63;
    const int w = tid >> 6;
    const int mh = (w & 1) * 32;
    const int nh = (w >> 1) * 64;
    const int g = lane >> 4, l15 = lane & 15;

    f32x4 acc[2][4] = {};

    for (int k0 = 0; k0 < K; k0 += 32) {
        __syncthreads();
        {   // A: fp32 -> hi/lo, swizzled store
            int r_ = tid >> 2, g_ = tid & 3;
            const float* ap = A + (size_t)(m0 + r_) * K + k0 + g_ * 8;
            float av[8];
            *(float4*)(av)     = *(const float4*)(ap);
            *(float4*)(av + 4) = *(const float4*)(ap + 4);
            bfrag vh, vl;
            #pragma unroll
            for (int j = 0; j < 8; ++j) {
                ushort h = f2bf_rne(av[j]);
                vh[j] = (short)h;
                vl[j] = (short)f2bf_rne(av[j] - bf2f(h));
            }
            int c = sw_idx(r_, g_) * 8;
            *(bfrag*)&sAh[c] = vh;
            *(bfrag*)&sAl[c] = vl;
        }
        #pragma unroll
        for (int i = 0; i < 4; ++i) {   // B planes, swizzled store
            int c = tid + i * 256;
            int pl = c >> 9, idx2 = c & 511;
            int r_ = idx2 >> 2, g_ = idx2 & 3;
            int brow = min(n0 + r_, N - 1);
            const ushort* src = (pl ? Blo : Bhi) + (size_t)brow * Bld + k0 + g_ * 8;
            int cc = sw_idx(r_, g_) * 8;
            if (pl) *(bfrag*)&sBl[cc] = *(const bfrag*)src;
            else    *(bfrag*)&sBh[cc] = *(const bfrag*)src;
        }
        __syncthreads();

        bfrag ah[2], al[2], bh[4], bl[4];
        #pragma unroll
        for (int s = 0; s < 2; ++s) {
            int c = sw_idx(mh + s * 16 + l15, g) * 8;
            ah[s] = *(const bfrag*)&sAh[c];
            al[s] = *(const bfrag*)&sAl[c];
        }
        #pragma unroll
        for (int u = 0; u < 4; ++u) {
            int c = sw_idx(nh + u * 16 + l15, g) * 8;
            bh[u] = *(const bfrag*)&sBh[c];
            bl[u] = *(const bfrag*)&sBl[c];
        }
        #pragma unroll
        for (int s = 0; s < 2; ++s)
            #pragma unroll
            for (int u = 0; u < 4; ++u) {
                acc[s][u] = __builtin_amdgcn_mfma_f32_16x16x32_bf16(ah[s], bh[u], acc[s][u], 0, 0, 0);
                acc[s][u] = __builtin_amdgcn_mfma_f32_16x16x32_bf16(ah[s], bl[u], acc[s][u], 0, 0, 0);
                acc[s][u] = __builtin_amdgcn_mfma_f32_16x16x32_bf16(al[s], bh[u], acc[s][u], 0, 0, 0);
            }
    }

    #pragma unroll
    for (int s = 0; s < 2; ++s)
        #pragma unroll
        for (int u = 0; u < 4; ++u) {
            int col = n0 + nh + u * 16 + l15;
            if (col < N) {
                float bv = bias ? bias[col] : 0.f;
                #pragma unroll
                for (int rr = 0; rr < 4; ++rr) {
                    int row = m0 + mh + s * 16 + g * 4 + rr;
                    C[(size_t)row * ldc + col] = acc[s][u][rr] + bv;
                }
            }
        }
}

// ---------------------------------------------------------------------------
// k_fmean2: fmean[b][e] = mean_h f[b][h][e].  grid 256 (b*4+eq, 128 e each).
// ---------------------------------------------------------------------------
__global__ __launch_bounds__(256) void k_fmean2(const float* __restrict__ f,
                                                float* __restrict__ fmean)
{
    __shared__ float part[128];
    int blk = blockIdx.x;
    int b = blk >> 2, eq = blk & 3;
    int el = threadIdx.x & 127, half = threadIdx.x >> 7;
    int e = eq * 128 + el;
    const float* fb = f + (size_t)b * HW * EMB + e;
    float s = 0.f;
    int h0 = half * 98;
    for (int h = h0; h < h0 + 98; ++h) s += fb[(size_t)h * EMB];
    if (half) part[el] = s;
    __syncthreads();
    if (!half) fmean[b * EMB + e] = (s + part[el]) * (1.0f / HW);
}

// ---------------------------------------------------------------------------
// k_init2: hx0/cx0 = fmean @ {W_hi,W_ci}^T + bias.  grid 512 x 256 thr,
// 1 thread per output (K=512 dot). Also writes the initial hx bf16 planes.
// ---------------------------------------------------------------------------
__global__ __launch_bounds__(256) void k_init2(
    const float* __restrict__ fmean,
    const float* __restrict__ W_hi, const float* __restrict__ b_hi,
    const float* __restrict__ W_ci, const float* __restrict__ b_ci,
    float* __restrict__ hx, float* __restrict__ cx,
    ushort* __restrict__ hxp_h, ushort* __restrict__ hxp_l)
{
    int o = blockIdx.x * 256 + threadIdx.x;   // 0..131071
    int b = o >> 11, uu = o & 2047;
    bool isC = uu >= 1024;
    int u = uu & 1023;
    const float4* wr = (const float4*)((isC ? W_ci : W_hi) + (size_t)u * EMB);
    const float4* fm = (const float4*)(fmean + (size_t)b * EMB);
    float s = isC ? b_ci[u] : b_hi[u];
    #pragma unroll 8
    for (int k = 0; k < EMB / 4; ++k) {
        float4 wv = wr[k], xv = fm[k];
        s += wv.x*xv.x + wv.y*xv.y + wv.z*xv.z + wv.w*xv.w;
    }
    int idx = b * HID + u;
    if (isC) cx[idx] = s;
    else {
        hx[idx] = s;
        ushort hh = f2bf_rne(s);
        hxp_h[idx] = hh;
        hxp_l[idx] = f2bf_rne(s - bf2f(hh));
    }
}

// xs_f[t*64+b][:] = E[captions[b][t]][:]  (fp32; feeds the hoisted GEMM)
__global__ __launch_bounds__(128) void k_embed(const int* __restrict__ cap,
                                               const float* __restrict__ E,
                                               float* __restrict__ xs_f)
{
    int blk = blockIdx.x;
    int t = blk / BB, b = blk % BB;
    int c = cap[b * TT + t];
    const float4* src = (const float4*)(E + (size_t)c * EMB);
    float4* dst = (float4*)(xs_f + ((size_t)t * BB + b) * EMB);
    dst[threadIdx.x] = src[threadIdx.x];
}

// ---------------------------------------------------------------------------
// k_ha: ha[b][a] = hx[b].W2[a] + b2[a].  grid 256: block -> 16 a's x 8 b's.
// ---------------------------------------------------------------------------
__global__ __launch_bounds__(256) void k_ha(
    const float* __restrict__ hx, const float* __restrict__ W2,
    const float* __restrict__ b2, float* __restrict__ ha)
{
    __shared__ __align__(16) float hx_s[8][1028];
    __shared__ float part[256];
    const int tid = threadIdx.x;
    const int a0 = (blockIdx.x >> 3) * 16;
    const int b0 = (blockIdx.x & 7) * 8;

    for (int i = tid; i < 8 * 256; i += 256) {
        int r = i >> 8, c4 = i & 255;
        *(float4*)&hx_s[r][c4 * 4] = *(const float4*)(hx + (size_t)(b0 + r) * HID + c4 * 4);
    }
    __syncthreads();

    const int a_i = tid >> 4;
    const int b_i = (tid >> 1) & 7;
    const int half = tid & 1;
    const float4* wr = (const float4*)(W2 + (size_t)(a0 + a_i) * HID + half * 512);
    const float* xr = &hx_s[b_i][half * 512];
    float s = 0.f;
    #pragma unroll 8
    for (int i = 0; i < 128; ++i) {
        float4 w = wr[i];
        float4 x = *(const float4*)(xr + i * 4);
        s += w.x*x.x + w.y*x.y + w.z*x.z + w.w*x.w;
    }
    part[tid] = s;
    __syncthreads();
    if (!half)
        ha[(size_t)(b0 + b_i) * ATT + a0 + a_i] = part[tid] + part[tid + 1] + b2[a0 + a_i];
}

// ---------------------------------------------------------------------------
// k_att: one block per b (64 x 1024): logits -> softmax -> ctx -> planes.
// (R10-verified step structure; faster than the 256-block logits/ctx split.)
// ---------------------------------------------------------------------------
__global__ __launch_bounds__(1024) void k_att(
    const float* __restrict__ f, const float* __restrict__ fa,
    const float* __restrict__ ha, const float* __restrict__ V,
    ushort* __restrict__ ctx_hi, ushort* __restrict__ ctx_lo)
{
    __shared__ __align__(16) float smem[2048];
    const int b = blockIdx.x;
    const int tid = threadIdx.x;
    const int lane = tid & 63;
    const int wid = tid >> 6;

    float* ha_s = smem;          // 512
    float* V_s  = smem + 512;    // 512
    float* w_s  = smem + 1024;   // 256 (196 used)
    float* red  = smem + 1280;   // 256
    float* pc   = smem + 1536;   // 512

    if (tid < ATT) { ha_s[tid] = ha[b * ATT + tid]; V_s[tid] = V[tid]; }
    __syncthreads();

    for (int h = wid; h < HW; h += 16) {
        const float4* fr = (const float4*)(fa + ((size_t)b * HW + h) * ATT);
        float s = 0.f;
        #pragma unroll
        for (int q = 0; q < 2; ++q) {
            int i4 = q * 64 + lane;
            float4 fv = fr[i4];
            float4 hv = *(const float4*)&ha_s[i4 * 4];
            float4 vv = *(const float4*)&V_s[i4 * 4];
            s += tanh_fast(fv.x + hv.x) * vv.x + tanh_fast(fv.y + hv.y) * vv.y
               + tanh_fast(fv.z + hv.z) * vv.z + tanh_fast(fv.w + hv.w) * vv.w;
        }
        #pragma unroll
        for (int off = 32; off > 0; off >>= 1) s += __shfl_down(s, off);
        if (lane == 0) w_s[h] = s;
    }
    __syncthreads();

    float v = (tid < HW) ? w_s[tid] : -INFINITY;
    if (tid < 256) red[tid] = v;
    __syncthreads();
    for (int s2 = 128; s2 > 0; s2 >>= 1) {
        if (tid < s2) red[tid] = fmaxf(red[tid], red[tid + s2]);
        __syncthreads();
    }
    float mx = red[0];
    __syncthreads();
    float e = (tid < HW) ? __expf(v - mx) : 0.f;
    if (tid < 256) red[tid] = e;
    __syncthreads();
    for (int s2 = 128; s2 > 0; s2 >>= 1) {
        if (tid < s2) red[tid] += red[tid + s2];
        __syncthreads();
    }
    float inv = 1.0f / red[0];
    if (tid < HW) w_s[tid] = e * inv;
    __syncthreads();

    {
        int e0 = tid & 511, grp = tid >> 9;
        const float* fb = f + (size_t)b * HW * EMB + e0;
        float s = 0.f;
        int h0 = grp * 98;
        for (int h = h0; h < h0 + 98; ++h)
            s = fmaf(w_s[h], fb[(size_t)h * EMB], s);
        if (grp) pc[e0] = s;
        __syncthreads();
        if (!grp) {
            float c = s + pc[e0];
            ushort ch = f2bf_rne(c);
            ctx_hi[b * EMB + e0] = ch;
            ctx_lo[b * EMB + e0] = f2bf_rne(c - bf2f(ch));
        }
    }
}

// ---------------------------------------------------------------------------
// k_gates_lstm: recurrent half of the gates GEMM (K=1536: ctx 512 + hx 1024;
// xs.W_ih[:, :512] precomputed in gxs) + fused LSTM.
// grid 256 x 512 thr (8 waves). Wave (mt, kh): kh0 = ctx + hx[0:256) (24 kk),
// kh1 = hx[256:1024) (24 kk). ncol(l15) = (l15>>2)*1024 + bk*4 + (l15&3).
// Epilogue: 8KB LDS reduce + gxs + biases -> LSTM -> hx, cx, next hx planes
// (parity double-buffered), hx_all fp32.
// ---------------------------------------------------------------------------
__global__ __launch_bounds__(512) void k_gates_lstm(
    const float* __restrict__ gxs_t,                                  // [64][4096]
    const ushort* __restrict__ cth, const ushort* __restrict__ ctl,   // [64][512]
    const ushort* __restrict__ hxh, const ushort* __restrict__ hxl,   // [64][1024] read
    const ushort* __restrict__ wihh, const ushort* __restrict__ wihl, // [4096][1024]
    const ushort* __restrict__ whhh, const ushort* __restrict__ whhl, // [4096][1024]
    const float* __restrict__ b_ih, const float* __restrict__ b_hh,
    float* __restrict__ hx, float* __restrict__ cx,
    ushort* __restrict__ nxh, ushort* __restrict__ nxl,               // write planes
    float* __restrict__ hx_all_t)
{
    __shared__ float sg[2][64][16];   // 8 KB
    const int tid = threadIdx.x, bk = blockIdx.x;
    const int lane = tid & 63, wid = tid >> 6;
    const int mt = wid & 3, kh = wid >> 2;
    const int l15 = lane & 15, g = lane >> 4;
    const int arow = mt * 16 + l15;
    const int ncol = (l15 >> 2) * 1024 + bk * 4 + (l15 & 3);
    const int koff = g * 8;

    f32x4 acc0 = {}, acc1 = {};

    if (kh == 0) {
        {   // ctx . W_ih[:, 512:1024)  (16 kk)
            const ushort* ah = cth + (size_t)arow * 512 + koff;
            const ushort* al = ctl + (size_t)arow * 512 + koff;
            const ushort* bh = wihh + (size_t)ncol * 1024 + 512 + koff;
            const ushort* bl = wihl + (size_t)ncol * 1024 + 512 + koff;
            #pragma unroll 4
            for (int kk = 0; kk < 16; ++kk) {
                bfrag a_h = *(const bfrag*)(ah + kk * 32);
                bfrag a_l = *(const bfrag*)(al + kk * 32);
                bfrag b_h = *(const bfrag*)(bh + kk * 32);
                bfrag b_l = *(const bfrag*)(bl + kk * 32);
                acc0 = __builtin_amdgcn_mfma_f32_16x16x32_bf16(a_h, b_h, acc0, 0, 0, 0);
                acc1 = __builtin_amdgcn_mfma_f32_16x16x32_bf16(a_h, b_l, acc1, 0, 0, 0);
                acc1 = __builtin_amdgcn_mfma_f32_16x16x32_bf16(a_l, b_h, acc1, 0, 0, 0);
            }
        }
        {   // hx[0:256) . W_hh[:, 0:256)  (8 kk)
            const ushort* ah = hxh + (size_t)arow * 1024 + koff;
            const ushort* al = hxl + (size_t)arow * 1024 + koff;
            const ushort* bh = whhh + (size_t)ncol * 1024 + koff;
            const ushort* bl = whhl + (size_t)ncol * 1024 + koff;
            #pragma unroll 4
            for (int kk = 0; kk < 8; ++kk) {
                bfrag a_h = *(const bfrag*)(ah + kk * 32);
                bfrag a_l = *(const bfrag*)(al + kk * 32);
                bfrag b_h = *(const bfrag*)(bh + kk * 32);
                bfrag b_l = *(const bfrag*)(bl + kk * 32);
                acc0 = __builtin_amdgcn_mfma_f32_16x16x32_bf16(a_h, b_h, acc0, 0, 0, 0);
                acc1 = __builtin_amdgcn_mfma_f32_16x16x32_bf16(a_h, b_l, acc1, 0, 0, 0);
                acc1 = __builtin_amdgcn_mfma_f32_16x16x32_bf16(a_l, b_h, acc1, 0, 0, 0);
            }
        }
    } else {
        // hx[256:1024) . W_hh[:, 256:1024)  (24 kk)
        const ushort* ah = hxh + (size_t)arow * 1024 + 256 + koff;
        const ushort* al = hxl + (size_t)arow * 1024 + 256 + koff;
        const ushort* bh = whhh + (size_t)ncol * 1024 + 256 + koff;
        const ushort* bl = whhl + (size_t)ncol * 1024 + 256 + koff;
        #pragma unroll 4
        for (int kk = 0; kk < 24; ++kk) {
            bfrag a_h = *(const bfrag*)(ah + kk * 32);
            bfrag a_l = *(const bfrag*)(al + kk * 32);
            bfrag b_h = *(const bfrag*)(bh + kk * 32);
            bfrag b_l = *(const bfrag*)(bl + kk * 32);
            acc0 = __builtin_amdgcn_mfma_f32_16x16x32_bf16(a_h, b_h, acc0, 0, 0, 0);
            acc1 = __builtin_amdgcn_mfma_f32_16x16x32_bf16(a_h, b_l, acc1, 0, 0, 0);
            acc1 = __builtin_amdgcn_mfma_f32_16x16x32_bf16(a_l, b_h, acc1, 0, 0, 0);
        }
    }

    #pragma unroll
    for (int rr = 0; rr < 4; ++rr)
        sg[kh][mt * 16 + g * 4 + rr][l15] = acc0[rr] + acc1[rr];
    __syncthreads();

    if (tid < 256) {
        int b = tid >> 2, uu = tid & 3;
        int u = bk * 4 + uu;
        const float* gx = gxs_t + (size_t)b * 4096;
        float gi = sg[0][b][uu]      + sg[1][b][uu]      + gx[u]        + b_ih[u]        + b_hh[u];
        float gf = sg[0][b][4 + uu]  + sg[1][b][4 + uu]  + gx[1024 + u] + b_ih[1024 + u] + b_hh[1024 + u];
        float gg = sg[0][b][8 + uu]  + sg[1][b][8 + uu]  + gx[2048 + u] + b_ih[2048 + u] + b_hh[2048 + u];
        float go = sg[0][b][12 + uu] + sg[1][b][12 + uu] + gx[3072 + u] + b_ih[3072 + u] + b_hh[3072 + u];
        int idx = b * 1024 + u;
        float c = sigmoid_fast(gf) * cx[idx] + sigmoid_fast(gi) * tanh_fast(gg);
        float h = sigmoid_fast(go) * tanh_fast(c);
        cx[idx] = c;
        hx[idx] = h;
        hx_all_t[idx] = h;
        ushort hh = f2bf_rne(h);
        nxh[idx] = hh;
        nxl[idx] = f2bf_rne(h - bf2f(hh));
    }
}

// ---------------------------------------------------------------------------
extern "C" void kernel_launch(void* const* d_in, const int* in_sizes, int n_in,
                              void* d_out, int out_size, void* d_ws, size_t ws_size,
                              hipStream_t stream) {
    const float* features = (const float*)d_in[0];
    const int*   captions = (const int*)d_in[1];
    const float* E      = (const float*)d_in[3];
    const float* W_feat = (const float*)d_in[4];
    const float* b_feat = (const float*)d_in[5];
    const float* W1     = (const float*)d_in[6];
    const float* b1     = (const float*)d_in[7];
    const float* W2     = (const float*)d_in[8];
    const float* b2     = (const float*)d_in[9];
    const float* V      = (const float*)d_in[10];
    // d_in[11] bV: softmax-invariant, unused
    const float* W_hi   = (const float*)d_in[12];
    const float* b_hi   = (const float*)d_in[13];
    const float* W_ci   = (const float*)d_in[14];
    const float* b_ci   = (const float*)d_in[15];
    const float* W_ih   = (const float*)d_in[16];
    const float* b_ih   = (const float*)d_in[17];
    const float* W_hh   = (const float*)d_in[18];
    const float* b_hh   = (const float*)d_in[19];
    const float* W_out  = (const float*)d_in[20];
    const float* b_out  = (const float*)d_in[21];
    float* out = (float*)d_out;

    // ---- workspace layout ----
    float* ws = (float*)d_ws;
    float* f_buf   = ws;                          // 6,422,528
    float* fa_buf  = f_buf + 6422528;             // 6,422,528
    float* fmean   = fa_buf + 6422528;            // 32,768
    float* hx      = fmean + 32768;               // 65,536
    float* cx      = hx + 65536;                  // 65,536
    float* hx_all  = cx + 65536;                  // 1,310,720
    float* ha      = hx_all + 1310720;            // 32,768
    float* xs_f    = ha + 32768;                  // 622,592
    float* gxs     = xs_f + 622592;               // 1216*4096 = 4,980,736
    ushort* p = (ushort*)(gxs + 4980736);
    ushort* wfeat_hi = p;            p += 1048576;
    ushort* wfeat_lo = p;            p += 1048576;
    ushort* w1_hi    = p;            p += 262144;
    ushort* w1_lo    = p;            p += 262144;
    ushort* wih_hi   = p;            p += 4194304;
    ushort* wih_lo   = p;            p += 4194304;
    ushort* whh_hi   = p;            p += 4194304;
    ushort* whh_lo   = p;            p += 4194304;
    ushort* ctx_hi   = p;            p += 32768;
    ushort* ctx_lo   = p;            p += 32768;
    ushort* hxp      = p;            p += 262144;   // [2 bufs][hi|lo][65536]
    // W_out planes reuse f_buf+fa_buf region after the step loop (41MB <= 51MB)
    ushort* wout_hi = (ushort*)f_buf;
    ushort* wout_lo = wout_hi + 10240000;

    // ---- precompute ----
    k_split<<<1048576 / 4 / 256, 256, 0, stream>>>(W_feat, wfeat_hi, wfeat_lo, 1048576);
    k_split<<<262144 / 4 / 256, 256, 0, stream>>>(W1, w1_hi, w1_lo, 262144);
    k_split<<<4194304 / 4 / 256, 256, 0, stream>>>(W_ih, wih_hi, wih_lo, 4194304);
    k_split<<<4194304 / 4 / 256, 256, 0, stream>>>(W_hh, whh_hi, whh_lo, 4194304);
    k_embed<<<STEPS * BB, 128, 0, stream>>>(captions, E, xs_f);
    // f = features @ W_feat^T + b_feat  [12544,512], K=2048
    mfma_g<true><<<784, 256, 0, stream>>>(
        features, wfeat_hi, wfeat_lo, b_feat, f_buf, 512, 2048, 2048, 512, 4, 196);
    // fa = f @ W1^T + b1  [12544,512], K=512
    mfma_g<true><<<784, 256, 0, stream>>>(
        f_buf, w1_hi, w1_lo, b1, fa_buf, 512, 512, 512, 512, 4, 196);
    // gxs = xs_flat @ W_ih[:, 0:512]^T  [1216,4096], K=512, Bld=1024, no bias
    mfma_g<false><<<608, 256, 0, stream>>>(
        xs_f, wih_hi, wih_lo, nullptr, gxs, 4096, 512, 1024, 4096, 32, 19);
    k_fmean2<<<256, 256, 0, stream>>>(f_buf, fmean);
    k_init2<<<512, 256, 0, stream>>>(fmean, W_hi, b_hi, W_ci, b_ci,
                                     hx, cx, hxp, hxp + 65536);

    // ---- recurrent steps: 3 dispatches per step ----
    for (int t = 0; t < STEPS; ++t) {
        ushort* hx_rd = hxp + (size_t)(t & 1) * 131072;
        ushort* hx_wr = hxp + (size_t)((t + 1) & 1) * 131072;
        k_ha<<<256, 256, 0, stream>>>(hx, W2, b2, ha);
        k_att<<<BB, 1024, 0, stream>>>(f_buf, fa_buf, ha, V, ctx_hi, ctx_lo);
        k_gates_lstm<<<256, 512, 0, stream>>>(
            gxs + (size_t)t * BB * 4096,
            ctx_hi, ctx_lo, hx_rd, hx_rd + 65536,
            wih_hi, wih_lo, whh_hi, whh_lo, b_ih, b_hh,
            hx, cx, hx_wr, hx_wr + 65536,
            hx_all + (size_t)t * BB * HID);
    }

    // ---- vocab projection over all steps: [1216,10000], K=1024 ----
    k_split<<<10240000 / 4 / 256, 256, 0, stream>>>(W_out, wout_hi, wout_lo, 10240000);
    mfma_g<false><<<1501, 256, 0, stream>>>(
        hx_all, wout_hi, wout_lo, b_out, out, VOCAB, HID, 1024, VOCAB, 79, 19);
}